// Round 1
// 250.140 us; speedup vs baseline: 1.0036x; 1.0036x over previous
//
#include <hip/hip_runtime.h>

typedef __bf16    bf16x8 __attribute__((ext_vector_type(8)));
typedef __bf16    bf16x4 __attribute__((ext_vector_type(4)));
typedef float     f32x4  __attribute__((ext_vector_type(4)));

#define BM 128
#define BN 128
#define BK 64

// async global->LDS, 16B per lane. LDS dest must be wave-uniform base + lane*16.
__device__ __forceinline__ void gload_lds16(const __bf16* g, __bf16* l) {
  __builtin_amdgcn_global_load_lds(
      (const __attribute__((address_space(1))) void*)g,
      (__attribute__((address_space(3))) void*)l,
      16, 0, 0);
}

// One launch converts x (8192 blocks) + Wq/Wk/Wv (3072 blocks) to bf16.
// Block 0 additionally zero-inits the row-sum accumulator.
__global__ void cvt_all(const float* __restrict__ x, const float* __restrict__ Wq,
                        const float* __restrict__ Wk, const float* __restrict__ Wv,
                        __bf16* __restrict__ xb, __bf16* __restrict__ Wqk,
                        __bf16* __restrict__ Wvb, float* __restrict__ lsum) {
  int b = blockIdx.x;
  if (b == 0) {
    for (int j = threadIdx.x; j < 8192; j += 256) lsum[j] = 0.f;
  }
  const float* src;
  __bf16* dst;
  int i;
  if (b < 8192) {
    src = x; dst = xb; i = b * 256 + threadIdx.x;
  } else {
    b -= 8192;
    const int mat = b >> 10;
    i = (b & 1023) * 256 + threadIdx.x;
    src = (mat == 0) ? Wq : (mat == 1) ? Wk : Wv;
    dst = (mat == 0) ? Wqk : (mat == 1) ? (Wqk + 1048576) : Wvb;
  }
  float4 v = ((const float4*)src)[i];
  bf16x4 o;
  o[0] = (__bf16)v.x; o[1] = (__bf16)v.y; o[2] = (__bf16)v.z; o[3] = (__bf16)v.w;
  ((bf16x4*)dst)[i] = o;
}

// ============================================================================
// 256x256 8-phase GEMM (m201 template, plain HIP): C[m,n] = sum_k A[m,k]B[n,k].
// 512 thr = 8 waves (2M x 4N), per-wave 128x64 output, acc[8][4] f32x4.
// LDS = ring of 4 half-K-tile slots (A[256][32] + B[256][32] bf16 = 32 KB each,
// 128 KB total). Slot h holds k in [h*32, h*32+32). Per slot: 2 phases
// (M-half 0 / M-half 1), 16 MFMA each; B-frags loaded once per slot.
// Staging: 1 unit (one matrix-half of a slot, 16 KB = 2 gload_lds/thread) per
// phase; unit u = phase+6 (prologue issues u0..u6), slot u>>1, A if u even.
// Counted vmcnt: checkpoint once per K-tile (end of odd slot): vmcnt(6)
// (= 3 units in flight), vmcnt(0) only for the last two checkpoints.
// Raw s_barrier (NOT __syncthreads -> would re-drain vmcnt(0)).
// Swizzle (rule #21, both-sides): LDS dest linear; global source k-group
// g = (chunk&3) ^ (row&3); read at group (quad ^ (row&3)) -> gets k=quad*8.
// Bank uniformity: 64B rows, 16B reads -> bank starts uniform 8 touches/bank.
// MODE 0: QK epilogue (bias + bf16 stores split to Q/K by gn>>10)
// MODE 2: scores epilogue (exp(v/32) -> bf16 + row sums via shfl+atomic)
// ============================================================================
template<int MODE>
__global__ __launch_bounds__(512, 2)
void gemm256(const __bf16* __restrict__ A, const __bf16* __restrict__ B,
             int lda, int ldb, int ldc, int K,
             long sA, long sB, long sC,
             const float* __restrict__ bias0, const float* __restrict__ bias1,
             float* __restrict__ lsum,
             __bf16* __restrict__ out0, __bf16* __restrict__ out1)
{
  // bijective XCD-chunked swizzle (nwg % 8 == 0 for both launches)
  const int nwg = gridDim.x * gridDim.y * gridDim.z;
  int lin = blockIdx.x + gridDim.x * (blockIdx.y + gridDim.y * blockIdx.z);
  lin = (lin & 7) * (nwg >> 3) + (lin >> 3);
  const int bx = lin % gridDim.x;
  const int rest = lin / gridDim.x;
  const int by = rest % gridDim.y;
  const int bz = rest / gridDim.y;

  A += (long)bz * sA;
  B += (long)bz * sB;

  const int tid  = threadIdx.x;
  const int wave = tid >> 6;
  const int lane = tid & 63;
  const int quad = lane >> 4;
  const int l15  = lane & 15;
  const int bm0  = bx * 256;
  const int bn0  = by * 256;
  const int wm   = (wave >> 2) * 128;   // 2 M-waves
  const int wn   = (wave & 3) * 64;     // 4 N-waves

  __shared__ __align__(16) __bf16 As[4 * 8192];   // 4 slots x [256][32] = 64 KB
  __shared__ __align__(16) __bf16 Bs[4 * 8192];   // 64 KB

  f32x4 acc[8][4];
#pragma unroll
  for (int i = 0; i < 8; ++i)
#pragma unroll
    for (int j = 0; j < 4; ++j)
      acc[i][j] = (f32x4){0.f, 0.f, 0.f, 0.f};

  const int NH = K >> 5;                // number of 32-wide k-half slots

  // Stage addressing: chunk ch in [0,1024) covers elems [ch*8, ch*8+8) of a
  // 16 KB unit ([256][32] row-major, row = ch>>2). Thread does ch = tid and
  // ch = tid+512 (rows r0, r0+128). Source k-group g = (ch&3) ^ (row&3);
  // (tid+512)&3 == tid&3 and (r0+128)&3 == r0&3 -> same g for both chunks.
  const int r0 = tid >> 2;
  const int g0 = (tid & 3) ^ (r0 & 3);
  const __bf16* A0 = A + (size_t)(bm0 + r0) * lda + g0 * 8;
  const __bf16* A1 = A + (size_t)(bm0 + r0 + 128) * lda + g0 * 8;
  const __bf16* B0 = B + (size_t)(bn0 + r0) * ldb + g0 * 8;
  const __bf16* B1 = B + (size_t)(bn0 + r0 + 128) * ldb + g0 * 8;

  auto stageU = [&](int u) {            // unit u: slot u>>1, matrix = u&1
    const int s = u >> 1;
    if (s < NH) {
      if (u & 1) {
        __bf16* d = &Bs[(s & 3) * 8192 + tid * 8];
        gload_lds16(B0 + s * 32, d);
        gload_lds16(B1 + s * 32, d + 4096);
      } else {
        __bf16* d = &As[(s & 3) * 8192 + tid * 8];
        gload_lds16(A0 + s * 32, d);
        gload_lds16(A1 + s * 32, d + 4096);
      }
    }
  };

  // Fragment read offsets (elements). Row R -> R*32 + (quad^(R&3))*8; R&3==l15&3.
  const int gq   = (quad ^ (l15 & 3)) * 8;
  const int aoff = (wm + l15) * 32 + gq;
  const int boff = (wn + l15) * 32 + gq;

  // ---- prologue: slots 0,1 fully staged + 3 units of slots 2,3 in flight ----
  stageU(0); stageU(1); stageU(2); stageU(3);
  asm volatile("s_waitcnt vmcnt(4)" ::: "memory");
  stageU(4); stageU(5); stageU(6);
  asm volatile("s_waitcnt vmcnt(6)" ::: "memory");
  __builtin_amdgcn_s_barrier();
  __builtin_amdgcn_sched_barrier(0);

  for (int h = 0; h < NH; ++h) {
    const int P = (h & 3) * 8192;
    bf16x8 af[4], bfv[4];
    // ---- phase A: M-half 0 + all B-frags (8 ds_read_b128) ----
#pragma unroll
    for (int ni = 0; ni < 4; ++ni)
      bfv[ni] = *(const bf16x8*)&Bs[P + ni * 512 + boff];
#pragma unroll
    for (int mi = 0; mi < 4; ++mi)
      af[mi] = *(const bf16x8*)&As[P + mi * 512 + aoff];
    stageU(2 * h + 7);
    __builtin_amdgcn_s_barrier();
    __builtin_amdgcn_s_setprio(1);
#pragma unroll
    for (int mi = 0; mi < 4; ++mi)
#pragma unroll
      for (int ni = 0; ni < 4; ++ni)
        acc[mi][ni] = __builtin_amdgcn_mfma_f32_16x16x32_bf16(
            af[mi], bfv[ni], acc[mi][ni], 0, 0, 0);
    __builtin_amdgcn_s_setprio(0);
    __builtin_amdgcn_s_barrier();
    // ---- phase B: M-half 1 (4 ds_read_b128, B-frags reused) ----
#pragma unroll
    for (int mi = 0; mi < 4; ++mi)
      af[mi] = *(const bf16x8*)&As[P + 2048 + mi * 512 + aoff];
    stageU(2 * h + 8);
    __builtin_amdgcn_s_barrier();
    __builtin_amdgcn_s_setprio(1);
#pragma unroll
    for (int mi = 0; mi < 4; ++mi)
#pragma unroll
      for (int ni = 0; ni < 4; ++ni)
        acc[mi + 4][ni] = __builtin_amdgcn_mfma_f32_16x16x32_bf16(
            af[mi], bfv[ni], acc[mi + 4][ni], 0, 0, 0);
    __builtin_amdgcn_s_setprio(0);
    if (h & 1) {                         // checkpoint: once per K-tile
      if (h + 4 < NH) asm volatile("s_waitcnt vmcnt(6)" ::: "memory");
      else            asm volatile("s_waitcnt vmcnt(0)" ::: "memory");
    }
    __builtin_amdgcn_s_barrier();
    if (h & 1) __builtin_amdgcn_sched_barrier(0);
  }

  // ---- epilogue. C/D layout: row = quad*4+r, col = lane&15 ----
  if (MODE == 2) {
    const long zc = (long)bz * sC;
#pragma unroll
    for (int mi = 0; mi < 8; ++mi) {
#pragma unroll
      for (int r = 0; r < 4; ++r) {
        const int gm = bm0 + wm + mi * 16 + quad * 4 + r;
        float part = 0.f;
#pragma unroll
        for (int ni = 0; ni < 4; ++ni) {
          const int gn = bn0 + wn + ni * 16 + l15;
          const __bf16 eb = (__bf16)__expf(acc[mi][ni][r] * 0.03125f);
          out0[zc + (size_t)gm * ldc + gn] = eb;
          part += (float)eb;   // sum the rounded values PV will actually read
        }
        part += __shfl_xor(part, 1);
        part += __shfl_xor(part, 2);
        part += __shfl_xor(part, 4);
        part += __shfl_xor(part, 8);
        if (l15 == 0)
          atomicAdd(&lsum[bz * 2048 + gm], part);
      }
    }
  } else {  // MODE 0
#pragma unroll
    for (int mi = 0; mi < 8; ++mi) {
#pragma unroll
      for (int ni = 0; ni < 4; ++ni) {
        const int gn  = bn0 + wn + ni * 16 + l15;
        const int mat = gn >> 10;          // uniform per n-tile (256 | 1024)
        const int d   = gn & 1023;
        const float* bias = (mat == 0) ? bias0 : bias1;
        __bf16* dst = (mat == 0) ? out0 : out1;
#pragma unroll
        for (int r = 0; r < 4; ++r) {
          const int gm = bm0 + wm + mi * 16 + quad * 4 + r;
          dst[(size_t)gm * 1024 + d] = (__bf16)(acc[mi][ni][r] + bias[d]);
        }
      }
    }
  }
}

// ============================================================================
// 128x128 single-phase kernel (proven, m97 structure) — kept for VT and PV
// whose 256^2 grids would be only 128 WGs (half the CUs idle at 1 blk/CU).
// ============================================================================
template<int MODE>
__global__ __launch_bounds__(256, 2)
void gemm_bt(const __bf16* __restrict__ A, const __bf16* __restrict__ B,
             float* __restrict__ C,
             int lda, int ldb, int ldc, int K,
             long sA, long sB, long sC,
             const float* __restrict__ bias0, const float* __restrict__ bias1,
             float* __restrict__ lsum,
             __bf16* __restrict__ out0, __bf16* __restrict__ out1)
{
  A += (long)blockIdx.z * sA;
  B += (long)blockIdx.z * sB;

  const int tid  = threadIdx.x;
  const int wave = tid >> 6;
  const int lane = tid & 63;
  const int quad = lane >> 4;
  const int l15  = lane & 15;
  const int bm0  = blockIdx.x * BM;
  const int bn0  = blockIdx.y * BN;
  const int wm   = (wave >> 1) * 64;
  const int wn   = (wave & 1) * 64;

  __shared__ __align__(16) __bf16 As[BM * BK];   // 16 KB
  __shared__ __align__(16) __bf16 Bs[BN * BK];   // 16 KB

  f32x4 acc[4][4];
#pragma unroll
  for (int i = 0; i < 4; ++i)
#pragma unroll
    for (int j = 0; j < 4; ++j)
      acc[i][j] = (f32x4){0.f, 0.f, 0.f, 0.f};

  const __bf16* Ag[4];
  const __bf16* Bg[4];
#pragma unroll
  for (int c = 0; c < 4; ++c) {
    const int r  = c * 32 + (tid >> 3);
    const int g  = (tid & 7) ^ (r & 7);
    Ag[c] = A + (size_t)(bm0 + r) * lda + g * 8;
    Bg[c] = B + (size_t)(bn0 + r) * ldb + g * 8;
  }

  for (int k0 = 0; k0 < K; k0 += BK) {
#pragma unroll
    for (int c = 0; c < 4; ++c) {
      gload_lds16(Ag[c] + k0, &As[c * 2048 + tid * 8]);
      gload_lds16(Bg[c] + k0, &Bs[c * 2048 + tid * 8]);
    }
    __syncthreads();

#pragma unroll
    for (int kk = 0; kk < 2; ++kk) {
      bf16x8 af[4], bfv[4];
#pragma unroll
      for (int i = 0; i < 4; ++i) {
        const int R = wm + i * 16 + l15;
        af[i] = *(const bf16x8*)&As[R * BK + (((kk * 4 + quad) ^ (R & 7)) * 8)];
      }
#pragma unroll
      for (int i = 0; i < 4; ++i) {
        const int R = wn + i * 16 + l15;
        bfv[i] = *(const bf16x8*)&Bs[R * BK + (((kk * 4 + quad) ^ (R & 7)) * 8)];
      }
#pragma unroll
      for (int mi = 0; mi < 4; ++mi)
#pragma unroll
        for (int ni = 0; ni < 4; ++ni)
          acc[mi][ni] = __builtin_amdgcn_mfma_f32_16x16x32_bf16(
              af[mi], bfv[ni], acc[mi][ni], 0, 0, 0);
    }
    __syncthreads();
  }

  if (MODE == 3) {
    // PV: normalize by row sum while storing fp32.
#pragma unroll
    for (int mi = 0; mi < 4; ++mi) {
#pragma unroll
      for (int r = 0; r < 4; ++r) {
        const int gm = bm0 + wm + mi * 16 + quad * 4 + r;
        const float rv = 1.0f / lsum[blockIdx.z * 2048 + gm];
#pragma unroll
        for (int ni = 0; ni < 4; ++ni) {
          const int gn = bn0 + wn + ni * 16 + l15;
          C[(long)blockIdx.z * sC + (size_t)gm * ldc + gn] = acc[mi][ni][r] * rv;
        }
      }
    }
  } else {  // MODE 1 (VT)
#pragma unroll
    for (int mi = 0; mi < 4; ++mi) {
#pragma unroll
      for (int ni = 0; ni < 4; ++ni) {
        const int gn = bn0 + wn + ni * 16 + l15;
#pragma unroll
        for (int r = 0; r < 4; ++r) {
          const int gm = bm0 + wm + mi * 16 + quad * 4 + r;
          const int b = gn >> 11, s = gn & 2047;
          out0[(size_t)b * (1024 * 2048) + (size_t)gm * 2048 + s] =
              (__bf16)(acc[mi][ni][r] + bias0[gm]);
        }
      }
    }
  }
}

extern "C" void kernel_launch(void* const* d_in, const int* in_sizes, int n_in,
                              void* d_out, int out_size, void* d_ws, size_t ws_size,
                              hipStream_t stream) {
  const float* x  = (const float*)d_in[0];
  const float* Wq = (const float*)d_in[1];
  const float* bq = (const float*)d_in[2];
  const float* Wk = (const float*)d_in[3];
  const float* bk = (const float*)d_in[4];
  const float* Wv = (const float*)d_in[5];
  const float* bv = (const float*)d_in[6];
  float* out = (float*)d_out;

  // ws layout:
  //  [0,16M)    Q    bf16 [8192][1024]
  //  [16,32M)   K    bf16 [8192][1024]
  //  [32,48M)   Vt   bf16 [4][1024][2048]
  //  [48,64M)   xb   bf16 (projection phase only)
  //  [64,68M)   Wqk  bf16 [2048][1024] (projection phase only)
  //  [68,70M)   Wvb  bf16 [1024][1024] (projection phase only)
  //  [48,80M)   Sc   bf16 [4][2048][2048] exp-weights (aliases xb/Wqk/Wvb)
  //  [110M,+32K) lsum fp32 [8192] row sums (zeroed by cvt_all block 0)
  char* ws = (char*)d_ws;
  __bf16* Q    = (__bf16*)(ws);
  __bf16* Kb   = (__bf16*)(ws + (16ull << 20));
  __bf16* Vt   = (__bf16*)(ws + (32ull << 20));
  __bf16* xb   = (__bf16*)(ws + (48ull << 20));
  __bf16* Wqk  = (__bf16*)(ws + (64ull << 20));
  __bf16* Wvb  = (__bf16*)(ws + (68ull << 20));
  __bf16* Sc   = (__bf16*)(ws + (48ull << 20));
  float*  lsum = (float*)(ws + (110ull << 20));

  // fp32 -> bf16 (+ lsum zero-init), one launch
  cvt_all<<<11264, dim3(256), 0, stream>>>(x, Wq, Wk, Wv, xb, Wqk, Wvb, lsum);

  // QK: [8192,1024] @ [2048,1024]^T -> Q, K (bf16, +bias)   [256^2 8-phase]
  gemm256<0><<<dim3(32, 8, 1), dim3(512), 0, stream>>>(
      xb, Wqk, 1024, 1024, 1024, 1024,
      0L, 0L, 0L, bq, bk, nullptr, Q, Kb);

  // VT: Wv[1024,1024] @ xb[8192,1024]^T -> Vt[b][d][s] (bf16, +bias[d])
  gemm_bt<1><<<dim3(8, 64, 1), dim3(256), 0, stream>>>(
      Wvb, xb, nullptr, 1024, 1024, 0, 1024,
      0L, 0L, 0L, bv, nullptr, nullptr, Vt, nullptr);

  // scores: per batch Q[2048,1024] @ K[2048,1024]^T -> bf16 exp-weights + lsum
  gemm256<2><<<dim3(8, 8, 4), dim3(512), 0, stream>>>(
      Q, Kb, 1024, 1024, 2048, 1024,
      2048L * 1024, 2048L * 1024, 2048L * 2048,
      nullptr, nullptr, lsum, Sc, nullptr);

  // PV: per batch Sc[2048,2048](bf16) @ Vt[1024,2048]^T -> out fp32, /lsum
  gemm_bt<3><<<dim3(16, 8, 4), dim3(256), 0, stream>>>(
      Sc, Vt, out, 2048, 2048, 1024, 2048,
      2048L * 2048, 1024L * 2048, 2048L * 1024,
      nullptr, nullptr, lsum, nullptr, nullptr);
}

// Round 2
// 241.802 us; speedup vs baseline: 1.0382x; 1.0345x over previous
//
#include <hip/hip_runtime.h>

typedef __bf16    bf16x8 __attribute__((ext_vector_type(8)));
typedef __bf16    bf16x4 __attribute__((ext_vector_type(4)));
typedef float     f32x4  __attribute__((ext_vector_type(4)));

#define BM 128
#define BN 128
#define BK 64

// async global->LDS, 16B per lane. LDS dest must be wave-uniform base + lane*16.
__device__ __forceinline__ void gload_lds16(const __bf16* g, __bf16* l) {
  __builtin_amdgcn_global_load_lds(
      (const __attribute__((address_space(1))) void*)g,
      (__attribute__((address_space(3))) void*)l,
      16, 0, 0);
}

// One launch converts x (8192 blocks) + Wq/Wk/Wv (3072 blocks) to bf16.
// Block 0 additionally zero-inits the row-sum accumulator.
__global__ void cvt_all(const float* __restrict__ x, const float* __restrict__ Wq,
                        const float* __restrict__ Wk, const float* __restrict__ Wv,
                        __bf16* __restrict__ xb, __bf16* __restrict__ Wqk,
                        __bf16* __restrict__ Wvb, float* __restrict__ lsum) {
  int b = blockIdx.x;
  if (b == 0) {
    for (int j = threadIdx.x; j < 8192; j += 256) lsum[j] = 0.f;
  }
  const float* src;
  __bf16* dst;
  int i;
  if (b < 8192) {
    src = x; dst = xb; i = b * 256 + threadIdx.x;
  } else {
    b -= 8192;
    const int mat = b >> 10;
    i = (b & 1023) * 256 + threadIdx.x;
    src = (mat == 0) ? Wq : (mat == 1) ? Wk : Wv;
    dst = (mat == 0) ? Wqk : (mat == 1) ? (Wqk + 1048576) : Wvb;
  }
  float4 v = ((const float4*)src)[i];
  bf16x4 o;
  o[0] = (__bf16)v.x; o[1] = (__bf16)v.y; o[2] = (__bf16)v.z; o[3] = (__bf16)v.w;
  ((bf16x4*)dst)[i] = o;
}

// ============================================================================
// 256x256 8-phase GEMM (m201 template, plain HIP): C[m,n] = sum_k A[m,k]B[n,k].
// 512 thr = 8 waves (2M x 4N), per-wave 128x64 output, acc[8][4] f32x4.
// LDS = ring of 4 half-K-tile slots (A[256][32] + B[256][32] bf16 = 32 KB each,
// 128 KB total). Slot h holds k in [h*32, h*32+32). Per slot: 2 phases
// (M-half 0 / M-half 1), 16 MFMA each; B-frags loaded once per slot.
// Staging: 1 unit (one matrix-half of a slot, 16 KB = 2 gload_lds/thread) per
// phase; unit u = phase+6 (prologue issues u0..u6), slot u>>1, A if u even.
// Counted vmcnt: checkpoint once per K-tile (end of odd slot): vmcnt(6)
// (= 3 units in flight), vmcnt(0) only for the last two checkpoints.
// Raw s_barrier (NOT __syncthreads -> would re-drain vmcnt(0)).
//
// Swizzle (rule #21, both-sides; FIXED round 2): LDS dest linear; rows are
// 64 B so bank index = byte%128 = (R&1)*64 + cg*16. Using cg = quad^(R&3)
// (round 1) made lanes l and l+4 of each 8-lane issue group hit the same 16B
// chunk at different rows -> 3.1M conflict cycles. Now cg = quad^((R>>1)&3):
// (R&1, cg) is bijective over any 8 consecutive rows -> all 32 banks covered
// once per 8-lane group; lanes l,l+8 alias 2-way only (free, m136).
// Source side: g = (chunk&3) ^ ((row>>1)&3); (row+128)>>1 == row>>1 (mod 4)
// and (tid+512)&3 == tid&3, so one g per thread covers both chunks.
// MODE 0: QK epilogue (bias + bf16 stores split to Q/K by gn>>10)
// MODE 2: scores epilogue (exp(v/32) -> bf16 + row sums via shfl+atomic)
// ============================================================================
template<int MODE>
__global__ __launch_bounds__(512, 2)
void gemm256(const __bf16* __restrict__ A, const __bf16* __restrict__ B,
             int lda, int ldb, int ldc, int K,
             long sA, long sB, long sC,
             const float* __restrict__ bias0, const float* __restrict__ bias1,
             float* __restrict__ lsum,
             __bf16* __restrict__ out0, __bf16* __restrict__ out1)
{
  // bijective XCD-chunked swizzle (nwg % 8 == 0 for both launches)
  const int nwg = gridDim.x * gridDim.y * gridDim.z;
  int lin = blockIdx.x + gridDim.x * (blockIdx.y + gridDim.y * blockIdx.z);
  lin = (lin & 7) * (nwg >> 3) + (lin >> 3);
  const int bx = lin % gridDim.x;
  const int rest = lin / gridDim.x;
  const int by = rest % gridDim.y;
  const int bz = rest / gridDim.y;

  A += (long)bz * sA;
  B += (long)bz * sB;

  const int tid  = threadIdx.x;
  const int wave = tid >> 6;
  const int lane = tid & 63;
  const int quad = lane >> 4;
  const int l15  = lane & 15;
  const int bm0  = bx * 256;
  const int bn0  = by * 256;
  const int wm   = (wave >> 2) * 128;   // 2 M-waves
  const int wn   = (wave & 3) * 64;     // 4 N-waves

  __shared__ __align__(16) __bf16 As[4 * 8192];   // 4 slots x [256][32] = 64 KB
  __shared__ __align__(16) __bf16 Bs[4 * 8192];   // 64 KB

  f32x4 acc[8][4];
#pragma unroll
  for (int i = 0; i < 8; ++i)
#pragma unroll
    for (int j = 0; j < 4; ++j)
      acc[i][j] = (f32x4){0.f, 0.f, 0.f, 0.f};

  const int NH = K >> 5;                // number of 32-wide k-half slots

  // Stage addressing: chunk ch in [0,1024) covers elems [ch*8, ch*8+8) of a
  // 16 KB unit ([256][32] row-major, row = ch>>2). Thread does ch = tid and
  // ch = tid+512 (rows r0, r0+128). Source k-group g = (ch&3) ^ ((row>>1)&3).
  const int r0 = tid >> 2;
  const int g0 = (tid & 3) ^ ((r0 >> 1) & 3);
  const __bf16* A0 = A + (size_t)(bm0 + r0) * lda + g0 * 8;
  const __bf16* A1 = A + (size_t)(bm0 + r0 + 128) * lda + g0 * 8;
  const __bf16* B0 = B + (size_t)(bn0 + r0) * ldb + g0 * 8;
  const __bf16* B1 = B + (size_t)(bn0 + r0 + 128) * ldb + g0 * 8;

  auto stageU = [&](int u) {            // unit u: slot u>>1, matrix = u&1
    const int s = u >> 1;
    if (s < NH) {
      if (u & 1) {
        __bf16* d = &Bs[(s & 3) * 8192 + tid * 8];
        gload_lds16(B0 + s * 32, d);
        gload_lds16(B1 + s * 32, d + 4096);
      } else {
        __bf16* d = &As[(s & 3) * 8192 + tid * 8];
        gload_lds16(A0 + s * 32, d);
        gload_lds16(A1 + s * 32, d + 4096);
      }
    }
  };

  // Fragment read offsets (elements). Row R -> R*32 + (quad^((R>>1)&3))*8;
  // (R>>1)&3 == (l15>>1)&3 since wm, wn, mi*16 are all multiples of 8 rows.
  const int gq   = (quad ^ ((l15 >> 1) & 3)) * 8;
  const int aoff = (wm + l15) * 32 + gq;
  const int boff = (wn + l15) * 32 + gq;

  // ---- prologue: slots 0,1 fully staged + 3 units of slots 2,3 in flight ----
  stageU(0); stageU(1); stageU(2); stageU(3);
  asm volatile("s_waitcnt vmcnt(4)" ::: "memory");
  stageU(4); stageU(5); stageU(6);
  asm volatile("s_waitcnt vmcnt(6)" ::: "memory");
  __builtin_amdgcn_s_barrier();
  __builtin_amdgcn_sched_barrier(0);

  for (int h = 0; h < NH; ++h) {
    const int P = (h & 3) * 8192;
    bf16x8 af[4], bfv[4];
    // ---- phase A: M-half 0 + all B-frags (8 ds_read_b128) ----
#pragma unroll
    for (int ni = 0; ni < 4; ++ni)
      bfv[ni] = *(const bf16x8*)&Bs[P + ni * 512 + boff];
#pragma unroll
    for (int mi = 0; mi < 4; ++mi)
      af[mi] = *(const bf16x8*)&As[P + mi * 512 + aoff];
    stageU(2 * h + 7);
    __builtin_amdgcn_s_barrier();
    __builtin_amdgcn_s_setprio(1);
#pragma unroll
    for (int mi = 0; mi < 4; ++mi)
#pragma unroll
      for (int ni = 0; ni < 4; ++ni)
        acc[mi][ni] = __builtin_amdgcn_mfma_f32_16x16x32_bf16(
            af[mi], bfv[ni], acc[mi][ni], 0, 0, 0);
    __builtin_amdgcn_s_setprio(0);
    __builtin_amdgcn_s_barrier();
    // ---- phase B: M-half 1 (4 ds_read_b128, B-frags reused) ----
#pragma unroll
    for (int mi = 0; mi < 4; ++mi)
      af[mi] = *(const bf16x8*)&As[P + 2048 + mi * 512 + aoff];
    stageU(2 * h + 8);
    __builtin_amdgcn_s_barrier();
    __builtin_amdgcn_s_setprio(1);
#pragma unroll
    for (int mi = 0; mi < 4; ++mi)
#pragma unroll
      for (int ni = 0; ni < 4; ++ni)
        acc[mi + 4][ni] = __builtin_amdgcn_mfma_f32_16x16x32_bf16(
            af[mi], bfv[ni], acc[mi + 4][ni], 0, 0, 0);
    __builtin_amdgcn_s_setprio(0);
    if (h & 1) {                         // checkpoint: once per K-tile
      if (h + 4 < NH) asm volatile("s_waitcnt vmcnt(6)" ::: "memory");
      else            asm volatile("s_waitcnt vmcnt(0)" ::: "memory");
    }
    __builtin_amdgcn_s_barrier();
    if (h & 1) __builtin_amdgcn_sched_barrier(0);
  }

  // ---- epilogue. C/D layout: row = quad*4+r, col = lane&15 ----
  if (MODE == 2) {
    const long zc = (long)bz * sC;
#pragma unroll
    for (int mi = 0; mi < 8; ++mi) {
#pragma unroll
      for (int r = 0; r < 4; ++r) {
        const int gm = bm0 + wm + mi * 16 + quad * 4 + r;
        float part = 0.f;
#pragma unroll
        for (int ni = 0; ni < 4; ++ni) {
          const int gn = bn0 + wn + ni * 16 + l15;
          const __bf16 eb = (__bf16)__expf(acc[mi][ni][r] * 0.03125f);
          out0[zc + (size_t)gm * ldc + gn] = eb;
          part += (float)eb;   // sum the rounded values PV will actually read
        }
        part += __shfl_xor(part, 1);
        part += __shfl_xor(part, 2);
        part += __shfl_xor(part, 4);
        part += __shfl_xor(part, 8);
        if (l15 == 0)
          atomicAdd(&lsum[bz * 2048 + gm], part);
      }
    }
  } else {  // MODE 0
#pragma unroll
    for (int mi = 0; mi < 8; ++mi) {
#pragma unroll
      for (int ni = 0; ni < 4; ++ni) {
        const int gn  = bn0 + wn + ni * 16 + l15;
        const int mat = gn >> 10;          // uniform per n-tile (256 | 1024)
        const int d   = gn & 1023;
        const float* bias = (mat == 0) ? bias0 : bias1;
        __bf16* dst = (mat == 0) ? out0 : out1;
#pragma unroll
        for (int r = 0; r < 4; ++r) {
          const int gm = bm0 + wm + mi * 16 + quad * 4 + r;
          dst[(size_t)gm * 1024 + d] = (__bf16)(acc[mi][ni][r] + bias[d]);
        }
      }
    }
  }
}

// ============================================================================
// 128x128 single-phase kernel (proven, m97 structure) — kept for VT and PV
// whose 256^2 grids would be only 128 WGs (half the CUs idle at 1 blk/CU).
// ============================================================================
template<int MODE>
__global__ __launch_bounds__(256, 2)
void gemm_bt(const __bf16* __restrict__ A, const __bf16* __restrict__ B,
             float* __restrict__ C,
             int lda, int ldb, int ldc, int K,
             long sA, long sB, long sC,
             const float* __restrict__ bias0, const float* __restrict__ bias1,
             float* __restrict__ lsum,
             __bf16* __restrict__ out0, __bf16* __restrict__ out1)
{
  A += (long)blockIdx.z * sA;
  B += (long)blockIdx.z * sB;

  const int tid  = threadIdx.x;
  const int wave = tid >> 6;
  const int lane = tid & 63;
  const int quad = lane >> 4;
  const int l15  = lane & 15;
  const int bm0  = blockIdx.x * BM;
  const int bn0  = blockIdx.y * BN;
  const int wm   = (wave >> 1) * 64;
  const int wn   = (wave & 1) * 64;

  __shared__ __align__(16) __bf16 As[BM * BK];   // 16 KB
  __shared__ __align__(16) __bf16 Bs[BN * BK];   // 16 KB

  f32x4 acc[4][4];
#pragma unroll
  for (int i = 0; i < 4; ++i)
#pragma unroll
    for (int j = 0; j < 4; ++j)
      acc[i][j] = (f32x4){0.f, 0.f, 0.f, 0.f};

  const __bf16* Ag[4];
  const __bf16* Bg[4];
#pragma unroll
  for (int c = 0; c < 4; ++c) {
    const int r  = c * 32 + (tid >> 3);
    const int g  = (tid & 7) ^ (r & 7);
    Ag[c] = A + (size_t)(bm0 + r) * lda + g * 8;
    Bg[c] = B + (size_t)(bn0 + r) * ldb + g * 8;
  }

  for (int k0 = 0; k0 < K; k0 += BK) {
#pragma unroll
    for (int c = 0; c < 4; ++c) {
      gload_lds16(Ag[c] + k0, &As[c * 2048 + tid * 8]);
      gload_lds16(Bg[c] + k0, &Bs[c * 2048 + tid * 8]);
    }
    __syncthreads();

#pragma unroll
    for (int kk = 0; kk < 2; ++kk) {
      bf16x8 af[4], bfv[4];
#pragma unroll
      for (int i = 0; i < 4; ++i) {
        const int R = wm + i * 16 + l15;
        af[i] = *(const bf16x8*)&As[R * BK + (((kk * 4 + quad) ^ (R & 7)) * 8)];
      }
#pragma unroll
      for (int i = 0; i < 4; ++i) {
        const int R = wn + i * 16 + l15;
        bfv[i] = *(const bf16x8*)&Bs[R * BK + (((kk * 4 + quad) ^ (R & 7)) * 8)];
      }
#pragma unroll
      for (int mi = 0; mi < 4; ++mi)
#pragma unroll
        for (int ni = 0; ni < 4; ++ni)
          acc[mi][ni] = __builtin_amdgcn_mfma_f32_16x16x32_bf16(
              af[mi], bfv[ni], acc[mi][ni], 0, 0, 0);
    }
    __syncthreads();
  }

  if (MODE == 3) {
    // PV: normalize by row sum while storing fp32.
#pragma unroll
    for (int mi = 0; mi < 4; ++mi) {
#pragma unroll
      for (int r = 0; r < 4; ++r) {
        const int gm = bm0 + wm + mi * 16 + quad * 4 + r;
        const float rv = 1.0f / lsum[blockIdx.z * 2048 + gm];
#pragma unroll
        for (int ni = 0; ni < 4; ++ni) {
          const int gn = bn0 + wn + ni * 16 + l15;
          C[(long)blockIdx.z * sC + (size_t)gm * ldc + gn] = acc[mi][ni][r] * rv;
        }
      }
    }
  } else {  // MODE 1 (VT)
#pragma unroll
    for (int mi = 0; mi < 4; ++mi) {
#pragma unroll
      for (int ni = 0; ni < 4; ++ni) {
        const int gn = bn0 + wn + ni * 16 + l15;
#pragma unroll
        for (int r = 0; r < 4; ++r) {
          const int gm = bm0 + wm + mi * 16 + quad * 4 + r;
          const int b = gn >> 11, s = gn & 2047;
          out0[(size_t)b * (1024 * 2048) + (size_t)gm * 2048 + s] =
              (__bf16)(acc[mi][ni][r] + bias0[gm]);
        }
      }
    }
  }
}

extern "C" void kernel_launch(void* const* d_in, const int* in_sizes, int n_in,
                              void* d_out, int out_size, void* d_ws, size_t ws_size,
                              hipStream_t stream) {
  const float* x  = (const float*)d_in[0];
  const float* Wq = (const float*)d_in[1];
  const float* bq = (const float*)d_in[2];
  const float* Wk = (const float*)d_in[3];
  const float* bk = (const float*)d_in[4];
  const float* Wv = (const float*)d_in[5];
  const float* bv = (const float*)d_in[6];
  float* out = (float*)d_out;

  // ws layout:
  //  [0,16M)    Q    bf16 [8192][1024]
  //  [16,32M)   K    bf16 [8192][1024]
  //  [32,48M)   Vt   bf16 [4][1024][2048]
  //  [48,64M)   xb   bf16 (projection phase only)
  //  [64,68M)   Wqk  bf16 [2048][1024] (projection phase only)
  //  [68,70M)   Wvb  bf16 [1024][1024] (projection phase only)
  //  [48,80M)   Sc   bf16 [4][2048][2048] exp-weights (aliases xb/Wqk/Wvb)
  //  [110M,+32K) lsum fp32 [8192] row sums (zeroed by cvt_all block 0)
  char* ws = (char*)d_ws;
  __bf16* Q    = (__bf16*)(ws);
  __bf16* Kb   = (__bf16*)(ws + (16ull << 20));
  __bf16* Vt   = (__bf16*)(ws + (32ull << 20));
  __bf16* xb   = (__bf16*)(ws + (48ull << 20));
  __bf16* Wqk  = (__bf16*)(ws + (64ull << 20));
  __bf16* Wvb  = (__bf16*)(ws + (68ull << 20));
  __bf16* Sc   = (__bf16*)(ws + (48ull << 20));
  float*  lsum = (float*)(ws + (110ull << 20));

  // fp32 -> bf16 (+ lsum zero-init), one launch
  cvt_all<<<11264, dim3(256), 0, stream>>>(x, Wq, Wk, Wv, xb, Wqk, Wvb, lsum);

  // QK: [8192,1024] @ [2048,1024]^T -> Q, K (bf16, +bias)   [256^2 8-phase]
  gemm256<0><<<dim3(32, 8, 1), dim3(512), 0, stream>>>(
      xb, Wqk, 1024, 1024, 1024, 1024,
      0L, 0L, 0L, bq, bk, nullptr, Q, Kb);

  // VT: Wv[1024,1024] @ xb[8192,1024]^T -> Vt[b][d][s] (bf16, +bias[d])
  gemm_bt<1><<<dim3(8, 64, 1), dim3(256), 0, stream>>>(
      Wvb, xb, nullptr, 1024, 1024, 0, 1024,
      0L, 0L, 0L, bv, nullptr, nullptr, Vt, nullptr);

  // scores: per batch Q[2048,1024] @ K[2048,1024]^T -> bf16 exp-weights + lsum
  gemm256<2><<<dim3(8, 8, 4), dim3(512), 0, stream>>>(
      Q, Kb, 1024, 1024, 2048, 1024,
      2048L * 1024, 2048L * 1024, 2048L * 2048,
      nullptr, nullptr, lsum, Sc, nullptr);

  // PV: per batch Sc[2048,2048](bf16) @ Vt[1024,2048]^T -> out fp32, /lsum
  gemm_bt<3><<<dim3(16, 8, 4), dim3(256), 0, stream>>>(
      Sc, Vt, out, 2048, 2048, 1024, 2048,
      2048L * 2048, 1024L * 2048, 2048L * 1024,
      nullptr, nullptr, lsum, nullptr, nullptr);
}